// Round 7
// baseline (35774.399 us; speedup 1.0000x reference)
//
#include <hip/hip_runtime.h>
#include <stdint.h>
#include <math.h>

// Problem dims
#define Bn 256
#define Sn 512
#define En 256
#define Hn 256
#define Gn 1024            // 4*H
#define NSTEP 511          // S-1 decoder steps
#define MASK_VAL -100000.0

// Verified rounds 1-3,7-11: partitionable threefry + f64 compute -> absmax=0.
#define PARTITIONABLE 1

// ---------------------------------------------------------------- threefry
__device__ __forceinline__ uint32_t rotl32(uint32_t v, int d) {
  return (v << d) | (v >> (32 - d));
}

__device__ __forceinline__ void threefry2x32(uint32_t k0, uint32_t k1,
                                             uint32_t x0, uint32_t x1,
                                             uint32_t& o0, uint32_t& o1) {
  const uint32_t ks2 = k0 ^ k1 ^ 0x1BD11BDAu;
  x0 += k0; x1 += k1;
  x0 += x1; x1 = rotl32(x1, 13); x1 ^= x0;
  x0 += x1; x1 = rotl32(x1, 15); x1 ^= x0;
  x0 += x1; x1 = rotl32(x1, 26); x1 ^= x0;
  x0 += x1; x1 = rotl32(x1,  6); x1 ^= x0;
  x0 += k1; x1 += ks2 + 1u;
  x0 += x1; x1 = rotl32(x1, 17); x1 ^= x0;
  x0 += x1; x1 = rotl32(x1, 29); x1 ^= x0;
  x0 += x1; x1 = rotl32(x1, 16); x1 ^= x0;
  x0 += x1; x1 = rotl32(x1, 24); x1 ^= x0;
  x0 += ks2; x1 += k0 + 2u;
  x0 += x1; x1 = rotl32(x1, 13); x1 ^= x0;
  x0 += x1; x1 = rotl32(x1, 15); x1 ^= x0;
  x0 += x1; x1 = rotl32(x1, 26); x1 ^= x0;
  x0 += x1; x1 = rotl32(x1,  6); x1 ^= x0;
  x0 += k0; x1 += k1 + 3u;
  x0 += x1; x1 = rotl32(x1, 17); x1 ^= x0;
  x0 += x1; x1 = rotl32(x1, 29); x1 ^= x0;
  x0 += x1; x1 = rotl32(x1, 16); x1 ^= x0;
  x0 += x1; x1 = rotl32(x1, 24); x1 ^= x0;
  x0 += k1; x1 += ks2 + 4u;
  x0 += x1; x1 = rotl32(x1, 13); x1 ^= x0;
  x0 += x1; x1 = rotl32(x1, 15); x1 ^= x0;
  x0 += x1; x1 = rotl32(x1, 26); x1 ^= x0;
  x0 += x1; x1 = rotl32(x1,  6); x1 ^= x0;
  x0 += ks2; x1 += k0 + 5u;
  o0 = x0; o1 = x1;
}

__device__ __forceinline__ uint32_t random_word(uint32_t k0, uint32_t k1, uint32_t n) {
#if PARTITIONABLE
  uint32_t o0, o1;
  threefry2x32(k0, k1, 0u, n, o0, o1);
  return o0 ^ o1;
#else
  const uint32_t half = (Bn * Sn) / 2;
  uint32_t lane = (n < half) ? n : (n - half);
  uint32_t o0, o1;
  threefry2x32(k0, k1, lane, lane + half, o0, o1);
  return (n < half) ? o0 : o1;
#endif
}

__device__ __forceinline__ double sigmoid64(double x) {
  return 1.0 / (1.0 + exp(-x));
}

// ---------------------------------------------------------------- prep
__global__ __launch_bounds__(256) void k_wihe(const float* __restrict__ wemb,
                                              const float* __restrict__ wih,
                                              const float* __restrict__ bih,
                                              const float* __restrict__ bhh,
                                              double* __restrict__ wihe,
                                              double* __restrict__ bias) {
  int j = blockIdx.x * blockDim.x + threadIdx.x;
  if (j >= Gn) return;
  double a0 = 0.0, a1 = 0.0;
  for (int e = 0; e < En; ++e) {
    double w = (double)wih[j * En + e];
    a0 += (double)wemb[e] * w;
    a1 += (double)wemb[En + e] * w;
  }
  wihe[j] = a0;
  wihe[Gn + j] = a1;
  bias[j] = (double)bih[j] + (double)bhh[j];
}

__global__ __launch_bounds__(256) void k_keys(uint32_t* __restrict__ keys) {
  int j = blockIdx.x * blockDim.x + threadIdx.x;
  if (j >= NSTEP) return;
#if PARTITIONABLE
  uint32_t o0, o1;
  threefry2x32(0u, 1u, 0u, (uint32_t)j, o0, o1);
  keys[2 * j] = o0; keys[2 * j + 1] = o1;
#else
  uint32_t w[2];
  #pragma unroll
  for (int q = 0; q < 2; ++q) {
    uint32_t m = (uint32_t)(2 * j + q);
    uint32_t lane = (m < NSTEP) ? m : (m - NSTEP);
    uint32_t o0, o1;
    threefry2x32(0u, 1u, lane, lane + NSTEP, o0, o1);
    w[q] = (m < NSTEP) ? o0 : o1;
  }
  keys[2 * j] = w[0]; keys[2 * j + 1] = w[1];
#endif
}

// dst[k][j] = src[j][k]  (256x256 f32 transpose: Wq, Wref)
__global__ __launch_bounds__(256) void k_t32(const float* __restrict__ src,
                                             float* __restrict__ dst) {
  int idx = blockIdx.x * blockDim.x + threadIdx.x;
  int k = idx >> 8, j = idx & 255;
  dst[idx] = src[j * Hn + k];
}

// Packed gate-weight layout (proven spill-free in r14):
// whh2[((k4*1024 + j)*4 + r)] = Whh[j][k4*4 + r]
// -> per instr a wave loads 64 lanes x float4 = 1KB contiguous; per-thread
// element order still k-ascending (bit-identical accumulation).
__global__ __launch_bounds__(256) void k_pack_whh(const float* __restrict__ src,
                                                  float* __restrict__ dst) {
  int o = blockIdx.x * 256 + threadIdx.x;          // 64*1024*4 = 262144
  int r = o & 3, j = (o >> 2) & 1023, k4 = o >> 12;
  dst[o] = src[j * Hn + k4 * 4 + r];
}

__global__ __launch_bounds__(256) void k_init(float* __restrict__ out) {
  int idx = blockIdx.x * blockDim.x + threadIdx.x;
  if (idx < Bn) out[Bn * NSTEP + idx * Sn] = 0.0f;   // indices[:,0] = START
}

// ---------------------------------------------------------------- main
// Block b owns batch row b end-to-end (zero cross-block communication).
// r18 = r16 (27.26 ms best, absmax 0, zero spill) + two isolated deltas:
//  1. packed float4 gate weights (phase A VMEM instr 256 -> 64 per
//     thread-step, enc+dec; same elements, same k-ascending order).
//     Proven spill-free inside r14 (its WRITE_SIZE stayed 1.07e6 KB).
//  2. phase E c-loop unroll-2: two st[8] groups loaded together then
//     consumed in order -- both arrays declared AND consumed inside one
//     loop body (the only staging shape this compiler keeps in VGPRs).
// r17 lesson: refT stays [b][h][s] -- phase E's per-lane "scalar" loads
// are wave-coalesced 256B/instr (lane = sE); [b][s][h] float4 made each
// instr a 64-line gather and FETCH rose 24%.
// r13/r15 lesson (2x burned): register staging whose live range spans
// phases/barriers or uses runtime-indexed arrays -> SCRATCH (WRITE_SIZE
// 1e6 -> 2e8 KB signature). Gate on WRITE_SIZE every round.
struct AttnS {
  double qpart[4][256];   // 8 KB
  double p2[2][512];      // 8 KB
  double sg[2][512];      // 8 KB  gumbel, double-buffered by t&1
  float2 qv2[256];        // 2 KB  {qf, v} fused
};

__global__ __launch_bounds__(1024, 4) void k_main(
    const float* __restrict__ inp,
    const double* __restrict__ wihe_e, const double* __restrict__ bias_e,
    const float* __restrict__ whh2_e,
    const double* __restrict__ wihe_d, const double* __restrict__ bias_d,
    const float* __restrict__ whh2_d,
    const float* __restrict__ wrefT, const float* __restrict__ wqT,
    const float* __restrict__ v,
    float* __restrict__ refT,
    const uint32_t* __restrict__ keys,
    float* __restrict__ out) {
  __shared__ __align__(16) double sh_h[Hn];   // current h (f64)
  __shared__ double sh_g[Gn];                 // transformed gates
  __shared__ AttnS at;

  const int b   = blockIdx.x;
  const int tid = threadIdx.x;
  const int w   = tid >> 6;
  const int l   = tid & 63;
  const int gsel = tid >> 8;      // 0:i 1:f 2:g 3:o (wave-uniform)

  // per-thread gate-row constants (j = tid)
  const double bj_e = bias_e[tid], w0e = wihe_e[tid], w1e = wihe_e[Gn + tid];
  const double bj_d = bias_d[tid], w0d = wihe_d[tid], w1d = wihe_d[Gn + tid];
  const float vreg = (tid < Hn) ? v[tid] : 0.0f;

  double creg = 0.0;              // c for unit u = tid (threads 0..255)
  if (tid < Hn) sh_h[tid] = 0.0;
  __syncthreads();

  const float4* w4e = (const float4*)whh2_e + tid;   // stride 1024 float4 per k4
  const float4* w4d = (const float4*)whh2_d + tid;
  const int part = tid >> 8, tcol = tid & 255;

  // ================================================================ encoder
  for (int s = 0; s < Sn; ++s) {
    // cell gates: exact k-ascending order (packed float4 weights, same math)
    {
      double x0 = (double)inp[((size_t)b * Sn + s) * 2 + 0];
      double x1 = (double)inp[((size_t)b * Sn + s) * 2 + 1];
      double acc = bj_e + x0 * w0e + x1 * w1e;
      #pragma unroll 4
      for (int k4 = 0; k4 < 64; ++k4) {
        float4 wv = w4e[(size_t)k4 << 10];
        double2 h0 = *(const double2*)&sh_h[4 * k4];
        double2 h1 = *(const double2*)&sh_h[4 * k4 + 2];
        acc += h0.x * (double)wv.x;
        acc += h0.y * (double)wv.y;
        acc += h1.x * (double)wv.z;
        acc += h1.y * (double)wv.w;
      }
      sh_g[tid] = (gsel == 2) ? tanh(acc) : sigmoid64(acc);
    }
    __syncthreads();                       // S1
    if (tid < Hn) {
      double ti = sh_g[tid];
      double tf = sh_g[256 + tid];
      double tg = sh_g[512 + tid];
      double to = sh_g[768 + tid];
      double cn = tf * creg + ti * tg;     // == sig(gf)*c + sig(gi)*tanh(gg)
      double hn = to * tanh(cn);
      creg = cn;
      sh_h[tid] = hn;
    }
    __syncthreads();                       // S2
    // refproj column s (verified split-k pattern, f64 h)
    {
      double racc = 0.0;
      #pragma unroll 8
      for (int i = 0; i < 64; ++i) {
        int k = part * 64 + i;
        racc += sh_h[k] * (double)wrefT[(size_t)k * Hn + tcol];
      }
      at.qpart[part][tcol] = racc;
    }
    __syncthreads();                       // S3
    if (tid < Hn) {
      double r = (at.qpart[0][tid] + at.qpart[1][tid]) +
                 (at.qpart[2][tid] + at.qpart[3][tid]);
      refT[((size_t)b * Hn + tid) * Sn + s] = (float)r;
    }
  }

  // ================================================================ decoder
  int ch = 0;                               // START; uniform across threads
  unsigned mbits = (l == 0) ? 1u : 0u;      // bit k: s = l + 64k masked
  for (int t = 0; t < NSTEP; ++t) {
    const int par = t & 1;
    // A: cell (exact k-ascending order; packed float4 weights)
    {
      int col = __builtin_amdgcn_readfirstlane(ch);
      double x0 = (double)inp[((size_t)b * Sn + col) * 2 + 0];
      double x1 = (double)inp[((size_t)b * Sn + col) * 2 + 1];
      double acc = bj_d + x0 * w0d + x1 * w1d;
      #pragma unroll 4
      for (int k4 = 0; k4 < 64; ++k4) {
        float4 wv = w4d[(size_t)k4 << 10];
        double2 h0 = *(const double2*)&sh_h[4 * k4];
        double2 h1 = *(const double2*)&sh_h[4 * k4 + 2];
        acc += h0.x * (double)wv.x;
        acc += h0.y * (double)wv.y;
        acc += h1.x * (double)wv.z;
        acc += h1.y * (double)wv.w;
      }
      sh_g[tid] = (gsel == 2) ? tanh(acc) : sigmoid64(acc);
    }
    __syncthreads();                       // S1
    // B: h-update (waves 0-3) || gumbel precompute (waves 8-15, else idle).
    if (tid < Hn) {
      double ti = sh_g[tid];
      double tf = sh_g[256 + tid];
      double tg = sh_g[512 + tid];
      double to = sh_g[768 + tid];
      double cn = tf * creg + ti * tg;
      double hn = to * tanh(cn);
      creg = cn;
      sh_h[tid] = hn;
    } else if (tid >= 512) {
      const uint32_t k0 = keys[2 * t], k1 = keys[2 * t + 1];
      int s0 = tid - 512;
      uint32_t wrd = random_word(k0, k1, (uint32_t)(b * Sn + s0));
      float uf = __uint_as_float((wrd >> 9) | 0x3f800000u) - 1.0f;
      uf = fmaxf(uf, 1.17549435e-38f);
      at.sg[par][s0] = -log(-log((double)uf));
    }
    __syncthreads();                       // S2
    // C: q-projection (r12 pattern)
    {
      double qa = 0.0;
      #pragma unroll 8
      for (int i = 0; i < 64; ++i) {
        int k = part * 64 + i;
        qa += sh_h[k] * (double)wqT[(size_t)k * Hn + tcol];
      }
      at.qpart[part][tcol] = qa;
    }
    __syncthreads();                       // S3
    if (tid < Hn) {
      double q = (at.qpart[0][tid] + at.qpart[1][tid]) +
                 (at.qpart[2][tid] + at.qpart[3][tid]);
      at.qv2[tid] = make_float2((float)q, vreg);
    }
    __syncthreads();                       // S4
    // E: logits (tanhf, f64 acc, t-ascending -- bit-identical order).
    // unroll-2: two 8-deep groups loaded together, consumed in order;
    // both arrays live only inside this loop body (register-safe shape).
    {
      const int sE = tid & 511, ph = tid >> 9;
      const float* rT = refT + ((size_t)b * Hn + ph * 128) * Sn + sE;
      double la = 0.0;
      for (int c = 0; c < 16; c += 2) {
        float stA[8], stB[8];
        #pragma unroll
        for (int i = 0; i < 8; ++i)
          stA[i] = rT[(size_t)(c * 8 + i) * Sn];
        #pragma unroll
        for (int i = 0; i < 8; ++i)
          stB[i] = rT[(size_t)((c + 1) * 8 + i) * Sn];
        #pragma unroll
        for (int i = 0; i < 8; ++i) {
          int t2 = ph * 128 + c * 8 + i;
          float2 qv = at.qv2[t2];          // .x = qf[t2], .y = v[t2]
          la += (double)qv.y * (double)tanhf(qv.x + stA[i]);
        }
        #pragma unroll
        for (int i = 0; i < 8; ++i) {
          int t2 = ph * 128 + (c + 1) * 8 + i;
          float2 qv = at.qv2[t2];
          la += (double)qv.y * (double)tanhf(qv.x + stB[i]);
        }
      }
      at.p2[ph][sE] = la;
    }
    __syncthreads();                       // S5
    // F: inline sampling (register masks), bit-identical compare sequence
    double slv[8];
    {
      #pragma unroll
      for (int k = 0; k < 8; ++k) {
        int s2 = l + k * 64;
        slv[k] = (mbits >> k) & 1u ? (double)MASK_VAL
                                   : (at.p2[0][s2] + at.p2[1][s2]);
      }
      double bz = slv[0] + at.sg[par][l];
      int bi = l;
      #pragma unroll
      for (int k = 1; k < 8; ++k) {
        int s2 = l + k * 64;
        double z2 = slv[k] + at.sg[par][s2];
        if (z2 > bz || (z2 == bz && s2 < bi)) { bz = z2; bi = s2; }
      }
      #pragma unroll
      for (int m = 32; m >= 1; m >>= 1) {
        double oz = __shfl_xor(bz, m);
        int    oi = __shfl_xor(bi, m);
        if (oz > bz || (oz == bz && oi < bi)) { bz = oz; bi = oi; }
      }
      ch = bi;
    }
    // logsumexp (wave 1 only) + output writes
    if (w == 1) {
      double bm = slv[0];
      #pragma unroll
      for (int k = 1; k < 8; ++k) bm = fmax(bm, slv[k]);
      #pragma unroll
      for (int m = 32; m >= 1; m >>= 1) bm = fmax(bm, __shfl_xor(bm, m));
      double ps = 0.0;
      #pragma unroll
      for (int k = 0; k < 8; ++k) ps += exp(slv[k] - bm);
      #pragma unroll
      for (int m = 32; m >= 1; m >>= 1) ps += __shfl_xor(ps, m);
      if (l == 0) {
        double lse = bm + log(ps);
        double slch = at.p2[0][ch] + at.p2[1][ch];   // ch is never masked
        double lp = slch - lse;
        out[(size_t)b * NSTEP + t] = (float)lp;
        out[(size_t)Bn * NSTEP + (size_t)b * Sn + (t + 1)] = (float)ch;
      }
    }
    // register mask update (every thread, every wave)
    if ((ch & 63) == l) mbits |= 1u << (ch >> 6);
    // no trailing barrier: next step's S1..S5 separate p2/sg/qv2 hazards;
    // sg double-buffer isolates the next gumbel write from this step's reads
  }
}

// ---------------------------------------------------------------- launch
extern "C" void kernel_launch(void* const* d_in, const int* in_sizes, int n_in,
                              void* d_out, int out_size, void* d_ws, size_t ws_size,
                              hipStream_t stream) {
  const float* inp  = (const float*)d_in[0];
  const float* wemb = (const float*)d_in[1];
  const float* eWih = (const float*)d_in[2];
  const float* eWhh = (const float*)d_in[3];
  const float* ebih = (const float*)d_in[4];
  const float* ebhh = (const float*)d_in[5];
  const float* dWih = (const float*)d_in[6];
  const float* dWhh = (const float*)d_in[7];
  const float* dbih = (const float*)d_in[8];
  const float* dbhh = (const float*)d_in[9];
  const float* Wq   = (const float*)d_in[10];
  const float* Wref = (const float*)d_in[11];
  const float* v    = (const float*)d_in[12];
  float* out = (float*)d_out;

  char* ws = (char*)d_ws;
  size_t off = 0;
  auto alloc = [&](size_t bytes) -> void* {
    void* p = (void*)(ws + off);
    off += (bytes + 255) & ~(size_t)255;
    return p;
  };
  // total ~137 MB (proven workspace level)
  float*    refT   = (float*)   alloc((size_t)Bn * Sn * Hn * sizeof(float));   // 134 MB
  float*    whh2_e = (float*)   alloc((size_t)Hn * Gn * sizeof(float));        // 1 MB packed
  float*    whh2_d = (float*)   alloc((size_t)Hn * Gn * sizeof(float));        // 1 MB packed
  float*    wqT    = (float*)   alloc((size_t)Hn * Hn * sizeof(float));
  float*    wrefT  = (float*)   alloc((size_t)Hn * Hn * sizeof(float));
  double*   wihe_e = (double*)  alloc(2 * Gn * sizeof(double));
  double*   wihe_d = (double*)  alloc(2 * Gn * sizeof(double));
  double*   bias_e = (double*)  alloc(Gn * sizeof(double));
  double*   bias_d = (double*)  alloc(Gn * sizeof(double));
  uint32_t* keys   = (uint32_t*)alloc(2 * NSTEP * sizeof(uint32_t));
  (void)ws_size; (void)in_sizes; (void)n_in; (void)out_size;

  k_wihe<<<Gn / 256, 256, 0, stream>>>(wemb, eWih, ebih, ebhh, wihe_e, bias_e);
  k_wihe<<<Gn / 256, 256, 0, stream>>>(wemb, dWih, dbih, dbhh, wihe_d, bias_d);
  k_keys<<<2, 256, 0, stream>>>(keys);
  k_t32<<<(Hn * Hn) / 256, 256, 0, stream>>>(Wq, wqT);
  k_t32<<<(Hn * Hn) / 256, 256, 0, stream>>>(Wref, wrefT);
  k_pack_whh<<<(Hn * Gn) / 256, 256, 0, stream>>>(eWhh, whh2_e);
  k_pack_whh<<<(Hn * Gn) / 256, 256, 0, stream>>>(dWhh, whh2_d);
  k_init<<<1, 256, 0, stream>>>(out);

  k_main<<<Bn, 1024, 0, stream>>>(
      inp, wihe_e, bias_e, whh2_e, wihe_d, bias_d, whh2_d,
      wrefT, wqT, v, refT, keys, out);
}

// Round 8
// 27387.704 us; speedup vs baseline: 1.3062x; 1.3062x over previous
//
#include <hip/hip_runtime.h>
#include <stdint.h>
#include <math.h>

// Problem dims
#define Bn 256
#define Sn 512
#define En 256
#define Hn 256
#define Gn 1024            // 4*H
#define NSTEP 511          // S-1 decoder steps
#define MASK_VAL -100000.0

// Verified rounds 1-3,7-11: partitionable threefry + f64 compute -> absmax=0.
#define PARTITIONABLE 1

// ---------------------------------------------------------------- threefry
__device__ __forceinline__ uint32_t rotl32(uint32_t v, int d) {
  return (v << d) | (v >> (32 - d));
}

__device__ __forceinline__ void threefry2x32(uint32_t k0, uint32_t k1,
                                             uint32_t x0, uint32_t x1,
                                             uint32_t& o0, uint32_t& o1) {
  const uint32_t ks2 = k0 ^ k1 ^ 0x1BD11BDAu;
  x0 += k0; x1 += k1;
  x0 += x1; x1 = rotl32(x1, 13); x1 ^= x0;
  x0 += x1; x1 = rotl32(x1, 15); x1 ^= x0;
  x0 += x1; x1 = rotl32(x1, 26); x1 ^= x0;
  x0 += x1; x1 = rotl32(x1,  6); x1 ^= x0;
  x0 += k1; x1 += ks2 + 1u;
  x0 += x1; x1 = rotl32(x1, 17); x1 ^= x0;
  x0 += x1; x1 = rotl32(x1, 29); x1 ^= x0;
  x0 += x1; x1 = rotl32(x1, 16); x1 ^= x0;
  x0 += x1; x1 = rotl32(x1, 24); x1 ^= x0;
  x0 += ks2; x1 += k0 + 2u;
  x0 += x1; x1 = rotl32(x1, 13); x1 ^= x0;
  x0 += x1; x1 = rotl32(x1, 15); x1 ^= x0;
  x0 += x1; x1 = rotl32(x1, 26); x1 ^= x0;
  x0 += x1; x1 = rotl32(x1,  6); x1 ^= x0;
  x0 += k0; x1 += k1 + 3u;
  x0 += x1; x1 = rotl32(x1, 17); x1 ^= x0;
  x0 += x1; x1 = rotl32(x1, 29); x1 ^= x0;
  x0 += x1; x1 = rotl32(x1, 16); x1 ^= x0;
  x0 += x1; x1 = rotl32(x1, 24); x1 ^= x0;
  x0 += k1; x1 += ks2 + 4u;
  x0 += x1; x1 = rotl32(x1, 13); x1 ^= x0;
  x0 += x1; x1 = rotl32(x1, 15); x1 ^= x0;
  x0 += x1; x1 = rotl32(x1, 26); x1 ^= x0;
  x0 += x1; x1 = rotl32(x1,  6); x1 ^= x0;
  x0 += ks2; x1 += k0 + 5u;
  o0 = x0; o1 = x1;
}

__device__ __forceinline__ uint32_t random_word(uint32_t k0, uint32_t k1, uint32_t n) {
#if PARTITIONABLE
  uint32_t o0, o1;
  threefry2x32(k0, k1, 0u, n, o0, o1);
  return o0 ^ o1;
#else
  const uint32_t half = (Bn * Sn) / 2;
  uint32_t lane = (n < half) ? n : (n - half);
  uint32_t o0, o1;
  threefry2x32(k0, k1, lane, lane + half, o0, o1);
  return (n < half) ? o0 : o1;
#endif
}

__device__ __forceinline__ double sigmoid64(double x) {
  return 1.0 / (1.0 + exp(-x));
}

// ---------------------------------------------------------------- prep
__global__ __launch_bounds__(256) void k_wihe(const float* __restrict__ wemb,
                                              const float* __restrict__ wih,
                                              const float* __restrict__ bih,
                                              const float* __restrict__ bhh,
                                              double* __restrict__ wihe,
                                              double* __restrict__ bias) {
  int j = blockIdx.x * blockDim.x + threadIdx.x;
  if (j >= Gn) return;
  double a0 = 0.0, a1 = 0.0;
  for (int e = 0; e < En; ++e) {
    double w = (double)wih[j * En + e];
    a0 += (double)wemb[e] * w;
    a1 += (double)wemb[En + e] * w;
  }
  wihe[j] = a0;
  wihe[Gn + j] = a1;
  bias[j] = (double)bih[j] + (double)bhh[j];
}

__global__ __launch_bounds__(256) void k_keys(uint32_t* __restrict__ keys) {
  int j = blockIdx.x * blockDim.x + threadIdx.x;
  if (j >= NSTEP) return;
#if PARTITIONABLE
  uint32_t o0, o1;
  threefry2x32(0u, 1u, 0u, (uint32_t)j, o0, o1);
  keys[2 * j] = o0; keys[2 * j + 1] = o1;
#else
  uint32_t w[2];
  #pragma unroll
  for (int q = 0; q < 2; ++q) {
    uint32_t m = (uint32_t)(2 * j + q);
    uint32_t lane = (m < NSTEP) ? m : (m - NSTEP);
    uint32_t o0, o1;
    threefry2x32(0u, 1u, lane, lane + NSTEP, o0, o1);
    w[q] = (m < NSTEP) ? o0 : o1;
  }
  keys[2 * j] = w[0]; keys[2 * j + 1] = w[1];
#endif
}

// dst[k][j] = src[j][k]  (256x256 f32 transpose: Wq, Wref)
__global__ __launch_bounds__(256) void k_t32(const float* __restrict__ src,
                                             float* __restrict__ dst) {
  int idx = blockIdx.x * blockDim.x + threadIdx.x;
  int k = idx >> 8, j = idx & 255;
  dst[idx] = src[j * Hn + k];
}

// dst[k][j] = src[j][k]  (Whh: 1024 rows j, 256 cols k -> 256 x 1024)
__global__ __launch_bounds__(256) void k_t32w(const float* __restrict__ src,
                                              float* __restrict__ dst) {
  int idx = blockIdx.x * blockDim.x + threadIdx.x;   // 256*1024 elems
  int k = idx >> 10, j = idx & 1023;
  dst[idx] = src[j * Hn + k];
}

__global__ __launch_bounds__(256) void k_init(float* __restrict__ out) {
  int idx = blockIdx.x * blockDim.x + threadIdx.x;
  if (idx < Bn) out[Bn * NSTEP + idx * Sn] = 0.0f;   // indices[:,0] = START
}

// ---------------------------------------------------------------- main
// Block b owns batch row b end-to-end (zero cross-block communication).
// r19 = REVERT to r16 verbatim (verified best: 27.26 ms, absmax 0, VGPR 56,
// zero spill). r16 = r12 + gumbel offloaded to idle waves in phase B +
// qf/v fused into one float2 LDS read in phase E.
// Experiment ledger (all absmax 0):
//   r12 27.8 | r16 27.26 BEST | r14 29.5 (packed-f4+enc-fold) |
//   r17 29.1 (refT [b][s][h]: broke wave-coalescing, FETCH +24%) |
//   r13/r15 171/251 (cross-phase reg staging -> SCRATCH, WRITE 1e6->2e8) |
//   r18 35.8 (packed-f4 + E-unroll2: load-clumping, VALUBusy 58->38).
// Lessons locked in:
//  - scalar k-loop loads (256 independent) pipeline better than float4
//    clumps for this latency-bound shape; do NOT vectorize the weight loads.
//  - refT stays [b][h][s]: phase-E scalar loads are wave-coalesced
//    256B/instr (lane = sE).
//  - register staging must be declared AND consumed inside one loop body
//    (st[8] shape); anything spanning a barrier/phase goes to scratch.
//  - VALU-issue floor ~16 ms (f64 FMA 4cyc + tanh chains); busy time is
//    already there; only the 42% stall fraction is theoretically available,
//    and 5 structurally different attacks on it all regressed.
struct AttnS {
  double qpart[4][256];   // 8 KB
  double p2[2][512];      // 8 KB
  double sg[2][512];      // 8 KB  gumbel, double-buffered by t&1
  float2 qv2[256];        // 2 KB  {qf, v} fused
};

__global__ __launch_bounds__(1024, 4) void k_main(
    const float* __restrict__ inp,
    const double* __restrict__ wihe_e, const double* __restrict__ bias_e,
    const float* __restrict__ whhT_e,
    const double* __restrict__ wihe_d, const double* __restrict__ bias_d,
    const float* __restrict__ whhT_d,
    const float* __restrict__ wrefT, const float* __restrict__ wqT,
    const float* __restrict__ v,
    float* __restrict__ refT,
    const uint32_t* __restrict__ keys,
    float* __restrict__ out) {
  __shared__ __align__(16) double sh_h[Hn];   // current h (f64)
  __shared__ double sh_g[Gn];                 // transformed gates
  __shared__ AttnS at;

  const int b   = blockIdx.x;
  const int tid = threadIdx.x;
  const int w   = tid >> 6;
  const int l   = tid & 63;
  const int gsel = tid >> 8;      // 0:i 1:f 2:g 3:o (wave-uniform)

  // per-thread gate-row constants (j = tid)
  const double bj_e = bias_e[tid], w0e = wihe_e[tid], w1e = wihe_e[Gn + tid];
  const double bj_d = bias_d[tid], w0d = wihe_d[tid], w1d = wihe_d[Gn + tid];
  const float vreg = (tid < Hn) ? v[tid] : 0.0f;

  double creg = 0.0;              // c for unit u = tid (threads 0..255)
  if (tid < Hn) sh_h[tid] = 0.0;
  __syncthreads();

  const float* wcol_e = whhT_e + tid;
  const float* wcol_d = whhT_d + tid;
  const int part = tid >> 8, tcol = tid & 255;

  // ================================================================ encoder
  for (int s = 0; s < Sn; ++s) {
    // cell gates: exact k-ascending order (double2 reads, same math);
    // transform applied by the OWNING thread (same input -> same value)
    {
      double x0 = (double)inp[((size_t)b * Sn + s) * 2 + 0];
      double x1 = (double)inp[((size_t)b * Sn + s) * 2 + 1];
      double acc = bj_e + x0 * w0e + x1 * w1e;
      #pragma unroll 4
      for (int k = 0; k < Hn; k += 2) {
        double2 hv = *(const double2*)&sh_h[k];
        acc += hv.x * (double)wcol_e[(size_t)k << 10];
        acc += hv.y * (double)wcol_e[(size_t)(k + 1) << 10];
      }
      sh_g[tid] = (gsel == 2) ? tanh(acc) : sigmoid64(acc);
    }
    __syncthreads();                       // S1
    if (tid < Hn) {
      double ti = sh_g[tid];
      double tf = sh_g[256 + tid];
      double tg = sh_g[512 + tid];
      double to = sh_g[768 + tid];
      double cn = tf * creg + ti * tg;     // == sig(gf)*c + sig(gi)*tanh(gg)
      double hn = to * tanh(cn);
      creg = cn;
      sh_h[tid] = hn;
    }
    __syncthreads();                       // S2
    // refproj column s (verified split-k pattern, f64 h)
    {
      double racc = 0.0;
      #pragma unroll 8
      for (int i = 0; i < 64; ++i) {
        int k = part * 64 + i;
        racc += sh_h[k] * (double)wrefT[(size_t)k * Hn + tcol];
      }
      at.qpart[part][tcol] = racc;
    }
    __syncthreads();                       // S3
    if (tid < Hn) {
      double r = (at.qpart[0][tid] + at.qpart[1][tid]) +
                 (at.qpart[2][tid] + at.qpart[3][tid]);
      refT[((size_t)b * Hn + tid) * Sn + s] = (float)r;
    }
  }

  // ================================================================ decoder
  int ch = 0;                               // START; uniform across threads
  unsigned mbits = (l == 0) ? 1u : 0u;      // bit k: s = l + 64k masked
  for (int t = 0; t < NSTEP; ++t) {
    const int par = t & 1;
    // A: cell (exact k-ascending order; double2 reads; uniform column scalar)
    {
      int col = __builtin_amdgcn_readfirstlane(ch);
      double x0 = (double)inp[((size_t)b * Sn + col) * 2 + 0];
      double x1 = (double)inp[((size_t)b * Sn + col) * 2 + 1];
      double acc = bj_d + x0 * w0d + x1 * w1d;
      #pragma unroll 4
      for (int k = 0; k < Hn; k += 2) {
        double2 hv = *(const double2*)&sh_h[k];
        acc += hv.x * (double)wcol_d[(size_t)k << 10];
        acc += hv.y * (double)wcol_d[(size_t)(k + 1) << 10];
      }
      sh_g[tid] = (gsel == 2) ? tanh(acc) : sigmoid64(acc);
    }
    __syncthreads();                       // S1
    // B: h-update (waves 0-3) || gumbel precompute (waves 8-15, else idle).
    // sg double-buffer isolates this write from step t-1's sampling reads
    // (sampling t-1 reads sg[par^1]; S1 separates it from this phase anyway).
    if (tid < Hn) {
      double ti = sh_g[tid];
      double tf = sh_g[256 + tid];
      double tg = sh_g[512 + tid];
      double to = sh_g[768 + tid];
      double cn = tf * creg + ti * tg;
      double hn = to * tanh(cn);
      creg = cn;
      sh_h[tid] = hn;
    } else if (tid >= 512) {
      const uint32_t k0 = keys[2 * t], k1 = keys[2 * t + 1];
      int s0 = tid - 512;
      uint32_t wrd = random_word(k0, k1, (uint32_t)(b * Sn + s0));
      float uf = __uint_as_float((wrd >> 9) | 0x3f800000u) - 1.0f;
      uf = fmaxf(uf, 1.17549435e-38f);
      at.sg[par][s0] = -log(-log((double)uf));
    }
    __syncthreads();                       // S2
    // C: q-projection (r12 pattern)
    {
      double qa = 0.0;
      #pragma unroll 8
      for (int i = 0; i < 64; ++i) {
        int k = part * 64 + i;
        qa += sh_h[k] * (double)wqT[(size_t)k * Hn + tcol];
      }
      at.qpart[part][tcol] = qa;
    }
    __syncthreads();                       // S3
    if (tid < Hn) {
      double q = (at.qpart[0][tid] + at.qpart[1][tid]) +
                 (at.qpart[2][tid] + at.qpart[3][tid]);
      at.qv2[tid] = make_float2((float)q, vreg);
    }
    __syncthreads();                       // S4
    // E: logits: r12 exact (tanhf, f64 acc, t-ascending, 8-deep staging
    // declared INSIDE the c loop -- the only staging pattern this compiler
    // keeps in registers). qf+v as one float2 read.
    {
      const int sE = tid & 511, ph = tid >> 9;
      const float* rT = refT + ((size_t)b * Hn + ph * 128) * Sn + sE;
      double la = 0.0;
      for (int c = 0; c < 16; ++c) {
        float st[8];
        #pragma unroll
        for (int i = 0; i < 8; ++i)
          st[i] = rT[(size_t)(c * 8 + i) * Sn];
        #pragma unroll
        for (int i = 0; i < 8; ++i) {
          int t2 = ph * 128 + c * 8 + i;
          float2 qv = at.qv2[t2];          // .x = qf[t2], .y = v[t2]
          la += (double)qv.y * (double)tanhf(qv.x + st[i]);
        }
      }
      at.p2[ph][sE] = la;
    }
    __syncthreads();                       // S5
    // F: inline sampling (register masks), bit-identical compare sequence
    double slv[8];
    {
      #pragma unroll
      for (int k = 0; k < 8; ++k) {
        int s2 = l + k * 64;
        slv[k] = (mbits >> k) & 1u ? (double)MASK_VAL
                                   : (at.p2[0][s2] + at.p2[1][s2]);
      }
      double bz = slv[0] + at.sg[par][l];
      int bi = l;
      #pragma unroll
      for (int k = 1; k < 8; ++k) {
        int s2 = l + k * 64;
        double z2 = slv[k] + at.sg[par][s2];
        if (z2 > bz || (z2 == bz && s2 < bi)) { bz = z2; bi = s2; }
      }
      #pragma unroll
      for (int m = 32; m >= 1; m >>= 1) {
        double oz = __shfl_xor(bz, m);
        int    oi = __shfl_xor(bi, m);
        if (oz > bz || (oz == bz && oi < bi)) { bz = oz; bi = oi; }
      }
      ch = bi;
    }
    // logsumexp (wave 1 only) + output writes
    if (w == 1) {
      double bm = slv[0];
      #pragma unroll
      for (int k = 1; k < 8; ++k) bm = fmax(bm, slv[k]);
      #pragma unroll
      for (int m = 32; m >= 1; m >>= 1) bm = fmax(bm, __shfl_xor(bm, m));
      double ps = 0.0;
      #pragma unroll
      for (int k = 0; k < 8; ++k) ps += exp(slv[k] - bm);
      #pragma unroll
      for (int m = 32; m >= 1; m >>= 1) ps += __shfl_xor(ps, m);
      if (l == 0) {
        double lse = bm + log(ps);
        double slch = at.p2[0][ch] + at.p2[1][ch];   // ch is never masked
        double lp = slch - lse;
        out[(size_t)b * NSTEP + t] = (float)lp;
        out[(size_t)Bn * NSTEP + (size_t)b * Sn + (t + 1)] = (float)ch;
      }
    }
    // register mask update (every thread, every wave)
    if ((ch & 63) == l) mbits |= 1u << (ch >> 6);
    // no trailing barrier: next step's S1..S5 separate p2/sg/qv2 hazards;
    // sg double-buffer isolates the next gumbel write from this step's reads
  }
}

// ---------------------------------------------------------------- launch
extern "C" void kernel_launch(void* const* d_in, const int* in_sizes, int n_in,
                              void* d_out, int out_size, void* d_ws, size_t ws_size,
                              hipStream_t stream) {
  const float* inp  = (const float*)d_in[0];
  const float* wemb = (const float*)d_in[1];
  const float* eWih = (const float*)d_in[2];
  const float* eWhh = (const float*)d_in[3];
  const float* ebih = (const float*)d_in[4];
  const float* ebhh = (const float*)d_in[5];
  const float* dWih = (const float*)d_in[6];
  const float* dWhh = (const float*)d_in[7];
  const float* dbih = (const float*)d_in[8];
  const float* dbhh = (const float*)d_in[9];
  const float* Wq   = (const float*)d_in[10];
  const float* Wref = (const float*)d_in[11];
  const float* v    = (const float*)d_in[12];
  float* out = (float*)d_out;

  char* ws = (char*)d_ws;
  size_t off = 0;
  auto alloc = [&](size_t bytes) -> void* {
    void* p = (void*)(ws + off);
    off += (bytes + 255) & ~(size_t)255;
    return p;
  };
  // total ~137 MB (proven workspace level)
  float*    refT   = (float*)   alloc((size_t)Bn * Sn * Hn * sizeof(float));   // 134 MB
  float*    whhT_e = (float*)   alloc((size_t)Hn * Gn * sizeof(float));        // 1 MB
  float*    whhT_d = (float*)   alloc((size_t)Hn * Gn * sizeof(float));        // 1 MB
  float*    wqT    = (float*)   alloc((size_t)Hn * Hn * sizeof(float));
  float*    wrefT  = (float*)   alloc((size_t)Hn * Hn * sizeof(float));
  double*   wihe_e = (double*)  alloc(2 * Gn * sizeof(double));
  double*   wihe_d = (double*)  alloc(2 * Gn * sizeof(double));
  double*   bias_e = (double*)  alloc(Gn * sizeof(double));
  double*   bias_d = (double*)  alloc(Gn * sizeof(double));
  uint32_t* keys   = (uint32_t*)alloc(2 * NSTEP * sizeof(uint32_t));
  (void)ws_size; (void)in_sizes; (void)n_in; (void)out_size;

  k_wihe<<<Gn / 256, 256, 0, stream>>>(wemb, eWih, ebih, ebhh, wihe_e, bias_e);
  k_wihe<<<Gn / 256, 256, 0, stream>>>(wemb, dWih, dbih, dbhh, wihe_d, bias_d);
  k_keys<<<2, 256, 0, stream>>>(keys);
  k_t32<<<(Hn * Hn) / 256, 256, 0, stream>>>(Wq, wqT);
  k_t32<<<(Hn * Hn) / 256, 256, 0, stream>>>(Wref, wrefT);
  k_t32w<<<(Hn * Gn) / 256, 256, 0, stream>>>(eWhh, whhT_e);
  k_t32w<<<(Hn * Gn) / 256, 256, 0, stream>>>(dWhh, whhT_d);
  k_init<<<1, 256, 0, stream>>>(out);

  k_main<<<Bn, 1024, 0, stream>>>(
      inp, wihe_e, bias_e, whhT_e, wihe_d, bias_d, whhT_d,
      wrefT, wqT, v, refT, keys, out);
}